// Round 1
// baseline (37828.824 us; speedup 1.0000x reference)
//
#include <hip/hip_runtime.h>
#include <hip/hip_cooperative_groups.h>

namespace cg = cooperative_groups;

#define B_   64
#define S_   512
#define EMB_ 512
#define HID_ 1024

// ---------------------------------------------------------------------------
// Kernel A: X1[t][b][n] = emb[x[b][t]][:] @ Wi1[:,n] + b1[n]
// M = S*B = 32768 rows (m = t*64 + b), N = 1024, K = 512.
// Grid (N/64, M/128), 256 threads, per-thread 8x4 micro-tile.
// ---------------------------------------------------------------------------
__global__ __launch_bounds__(256) void embed_gemm(
    const int* __restrict__ x, const float* __restrict__ emb,
    const float* __restrict__ Wi1, const float* __restrict__ b1,
    float* __restrict__ X1)
{
    __shared__ int   tok[128];
    __shared__ float aT[32][132];   // [k][row], +4 pad
    __shared__ float bl[32][68];    // [k][col], +4 pad

    const int tid = threadIdx.x;
    const int m0  = blockIdx.y * 128;
    const int n0  = blockIdx.x * 64;

    if (tid < 128) {
        int m = m0 + tid;
        tok[tid] = x[(m & 63) * S_ + (m >> 6)];   // x[b][t]
    }
    __syncthreads();

    const int tx = tid & 15;   // col group: cols n0 + tx*4 .. +3
    const int ty = tid >> 4;   // row group: rows m0 + ty*8 .. +7

    float acc[8][4];
#pragma unroll
    for (int r = 0; r < 8; ++r)
#pragma unroll
        for (int c = 0; c < 4; ++c) acc[r][c] = 0.f;

    for (int kt = 0; kt < EMB_; kt += 32) {
        // stage A tile (gathered embedding rows), transposed into LDS
#pragma unroll
        for (int j = 0; j < 4; ++j) {
            int idx = tid + j * 256;            // 0..1023
            int r   = idx >> 3;
            int k4  = (idx & 7) * 4;
            float4 v = *(const float4*)(emb + (size_t)tok[r] * EMB_ + kt + k4);
            aT[k4 + 0][r] = v.x; aT[k4 + 1][r] = v.y;
            aT[k4 + 2][r] = v.z; aT[k4 + 3][r] = v.w;
        }
        // stage B tile
#pragma unroll
        for (int j = 0; j < 2; ++j) {
            int idx = tid + j * 256;            // 0..511
            int k   = idx >> 4;
            int c4  = (idx & 15) * 4;
            *(float4*)&bl[k][c4] =
                *(const float4*)(Wi1 + (size_t)(kt + k) * HID_ + n0 + c4);
        }
        __syncthreads();

#pragma unroll 4
        for (int k = 0; k < 32; ++k) {
            float4 a0 = *(const float4*)&aT[k][ty * 8];
            float4 a1 = *(const float4*)&aT[k][ty * 8 + 4];
            float4 bv = *(const float4*)&bl[k][tx * 4];
            float ar[8] = {a0.x, a0.y, a0.z, a0.w, a1.x, a1.y, a1.z, a1.w};
            float bc[4] = {bv.x, bv.y, bv.z, bv.w};
#pragma unroll
            for (int r = 0; r < 8; ++r)
#pragma unroll
                for (int c = 0; c < 4; ++c) acc[r][c] += ar[r] * bc[c];
        }
        __syncthreads();
    }

    float4 bias = *(const float4*)(b1 + n0 + tx * 4);
#pragma unroll
    for (int r = 0; r < 8; ++r) {
        int m = m0 + ty * 8 + r;
        float4 o;
        o.x = acc[r][0] + bias.x; o.y = acc[r][1] + bias.y;
        o.z = acc[r][2] + bias.z; o.w = acc[r][3] + bias.w;
        *(float4*)(X1 + (size_t)m * HID_ + n0 + tx * 4) = o;
    }
}

// ---------------------------------------------------------------------------
// Kernel B: persistent cooperative scan.
// 256 blocks x 256 threads; block owns cols [blk*4, blk*4+4) of Wh1/Wi2/Wh2
// (held in LDS, transposed, fp32). Pipelined: iteration i computes h1(i) and
// h2(i-1) (mutually independent), one grid.sync per iteration.
// h layout: h1buf[p] = hb + p*65536 ; h2buf[p] = hb + 131072 + p*65536.
// ---------------------------------------------------------------------------
__global__ __launch_bounds__(256, 1) void rnn_scan(
    const float* __restrict__ X1, const float* __restrict__ Wh1,
    const float* __restrict__ Wi2, const float* __restrict__ Wh2,
    const float* __restrict__ b2, float* __restrict__ hb)
{
    cg::grid_group grid = cg::this_grid();

    __shared__ float w1T[4][1028];   // [c][k], +4 pad to break bank aliasing
    __shared__ float w2T[4][1028];
    __shared__ float w3T[4][1028];
    __shared__ float h1c[64][132];   // [row][k-chunk], +4 pad
    __shared__ float h2c[64][132];

    const int tid  = threadIdx.x;
    const int col0 = blockIdx.x * 4;

    // Load this block's weight column slices (transposed) into LDS. One-time.
    for (int k = tid; k < HID_; k += 256) {
        float4 v1 = *(const float4*)(Wh1 + (size_t)k * HID_ + col0);
        float4 v2 = *(const float4*)(Wi2 + (size_t)k * HID_ + col0);
        float4 v3 = *(const float4*)(Wh2 + (size_t)k * HID_ + col0);
        w1T[0][k] = v1.x; w1T[1][k] = v1.y; w1T[2][k] = v1.z; w1T[3][k] = v1.w;
        w2T[0][k] = v2.x; w2T[1][k] = v2.y; w2T[2][k] = v2.z; w2T[3][k] = v2.w;
        w3T[0][k] = v3.x; w3T[1][k] = v3.y; w3T[2][k] = v3.z; w3T[3][k] = v3.w;
    }

    const int   row = tid >> 2;     // 0..63  (batch row)
    const int   c   = tid & 3;      // 0..3   (column within slice)
    const float b2v = b2[col0 + c];

    float* h1buf[2] = { hb,          hb + 65536 };
    float* h2buf[2] = { hb + 131072, hb + 196608 };

    __syncthreads();

    for (int i = 0; i <= S_; ++i) {
        const float* h1p = h1buf[(i + 1) & 1];   // h1(i-1)
        const float* h2p = h2buf[i & 1];         // h2(i-2)

        float acc1 = 0.f, accA = 0.f, accB = 0.f;

        for (int ck = 0; ck < HID_; ck += 128) {
            // stage h1/h2 chunks into LDS (coalesced float4)
#pragma unroll
            for (int j = 0; j < 8; ++j) {
                int idx = tid + j * 256;        // 0..2047
                int r   = idx >> 5;
                int k4  = (idx & 31) * 4;
                *(float4*)&h1c[r][k4] = *(const float4*)(h1p + r * HID_ + ck + k4);
                *(float4*)&h2c[r][k4] = *(const float4*)(h2p + r * HID_ + ck + k4);
            }
            __syncthreads();

#pragma unroll 4
            for (int kk = 0; kk < 128; kk += 4) {
                float4 hv1 = *(const float4*)&h1c[row][kk];
                float4 hv2 = *(const float4*)&h2c[row][kk];
                float4 wv1 = *(const float4*)&w1T[c][ck + kk];
                float4 wv2 = *(const float4*)&w2T[c][ck + kk];
                float4 wv3 = *(const float4*)&w3T[c][ck + kk];
                acc1 += hv1.x*wv1.x + hv1.y*wv1.y + hv1.z*wv1.z + hv1.w*wv1.w;
                accA += hv1.x*wv2.x + hv1.y*wv2.y + hv1.z*wv2.z + hv1.w*wv2.w;
                accB += hv2.x*wv3.x + hv2.y*wv3.y + hv2.z*wv3.z + hv2.w*wv3.w;
            }
            __syncthreads();
        }

        if (i < S_) {   // h1(i) = tanh(X1[i] + h1(i-1)@Wh1)
            float xv = X1[((size_t)i * B_ + row) * HID_ + col0 + c];
            h1buf[i & 1][row * HID_ + col0 + c] = tanhf(xv + acc1);
        }
        if (i >= 1) {   // h2(i-1) = tanh(h1(i-1)@Wi2 + b2 + h2(i-2)@Wh2)
            h2buf[(i + 1) & 1][row * HID_ + col0 + c] = tanhf(accA + accB + b2v);
        }
        if (i < S_) grid.sync();
    }
    // after loop: h2(S-1) sits in h2buf[1] (= hb + 196608)
}

// ---------------------------------------------------------------------------
// Kernel C: out[b] = sigmoid(h2_last[b,:] @ Wd + bd)
// ---------------------------------------------------------------------------
__global__ void dense_sigmoid(const float* __restrict__ h2,
                              const float* __restrict__ Wd,
                              const float* __restrict__ bd,
                              float* __restrict__ out)
{
    int b = blockIdx.x, lane = threadIdx.x;   // 64 threads
    float s = 0.f;
    for (int j = lane; j < HID_; j += 64) s += h2[b * HID_ + j] * Wd[j];
#pragma unroll
    for (int off = 32; off > 0; off >>= 1) s += __shfl_down(s, off, 64);
    if (lane == 0) out[b] = 1.f / (1.f + expf(-(s + bd[0])));
}

// ---------------------------------------------------------------------------
extern "C" void kernel_launch(void* const* d_in, const int* in_sizes, int n_in,
                              void* d_out, int out_size, void* d_ws, size_t ws_size,
                              hipStream_t stream)
{
    const int*   x   = (const int*)  d_in[0];
    const float* emb = (const float*)d_in[1];
    const float* Wi1 = (const float*)d_in[2];
    const float* Wh1 = (const float*)d_in[3];
    const float* b1  = (const float*)d_in[4];
    const float* Wi2 = (const float*)d_in[5];
    const float* Wh2 = (const float*)d_in[6];
    const float* b2  = (const float*)d_in[7];
    const float* Wd  = (const float*)d_in[8];
    const float* bd  = (const float*)d_in[9];
    float* out = (float*)d_out;

    // ws layout: X1 (S*B*HID fp32 = 134.2 MB) | 4 h buffers (4*64*1024 fp32 = 1 MB)
    float* X1 = (float*)d_ws;
    float* hb = X1 + (size_t)S_ * B_ * HID_;

    hipMemsetAsync(hb, 0, 4 * 65536 * sizeof(float), stream);

    dim3 gA(HID_ / 64, (S_ * B_) / 128);
    embed_gemm<<<gA, dim3(256), 0, stream>>>(x, emb, Wi1, b1, X1);

    const float* X1c = X1;
    void* args[] = { (void*)&X1c, (void*)&Wh1, (void*)&Wi2,
                     (void*)&Wh2, (void*)&b2, (void*)&hb };
    hipLaunchCooperativeKernel((const void*)rnn_scan, dim3(256), dim3(256),
                               args, 0, stream);

    dense_sigmoid<<<64, 64, 0, stream>>>(hb + 196608, Wd, bd, out);
}

// Round 2
// 34593.637 us; speedup vs baseline: 1.0935x; 1.0935x over previous
//
#include <hip/hip_runtime.h>
#include <hip/hip_cooperative_groups.h>

namespace cg = cooperative_groups;

#define B_   64
#define S_   512
#define EMB_ 512
#define HID_ 1024

// ---------------------------------------------------------------------------
// Kernel A: X1[t][b][n] = emb[x[b][t]][:] @ Wi1[:,n] + b1[n]
// M = S*B = 32768 rows (m = t*64 + b), N = 1024, K = 512.
// ---------------------------------------------------------------------------
__global__ __launch_bounds__(256) void embed_gemm(
    const int* __restrict__ x, const float* __restrict__ emb,
    const float* __restrict__ Wi1, const float* __restrict__ b1,
    float* __restrict__ X1)
{
    __shared__ int   tok[128];
    __shared__ float aT[32][132];   // [k][row], +4 pad
    __shared__ float bl[32][68];    // [k][col], +4 pad

    const int tid = threadIdx.x;
    const int m0  = blockIdx.y * 128;
    const int n0  = blockIdx.x * 64;

    if (tid < 128) {
        int m = m0 + tid;
        tok[tid] = x[(m & 63) * S_ + (m >> 6)];   // x[b][t]
    }
    __syncthreads();

    const int tx = tid & 15;   // col group: cols n0 + tx*4 .. +3
    const int ty = tid >> 4;   // row group: rows m0 + ty*8 .. +7

    float acc[8][4];
#pragma unroll
    for (int r = 0; r < 8; ++r)
#pragma unroll
        for (int c = 0; c < 4; ++c) acc[r][c] = 0.f;

    for (int kt = 0; kt < EMB_; kt += 32) {
#pragma unroll
        for (int j = 0; j < 4; ++j) {
            int idx = tid + j * 256;            // 0..1023
            int r   = idx >> 3;
            int k4  = (idx & 7) * 4;
            float4 v = *(const float4*)(emb + (size_t)tok[r] * EMB_ + kt + k4);
            aT[k4 + 0][r] = v.x; aT[k4 + 1][r] = v.y;
            aT[k4 + 2][r] = v.z; aT[k4 + 3][r] = v.w;
        }
#pragma unroll
        for (int j = 0; j < 2; ++j) {
            int idx = tid + j * 256;            // 0..511
            int k   = idx >> 4;
            int c4  = (idx & 15) * 4;
            *(float4*)&bl[k][c4] =
                *(const float4*)(Wi1 + (size_t)(kt + k) * HID_ + n0 + c4);
        }
        __syncthreads();

#pragma unroll 4
        for (int k = 0; k < 32; ++k) {
            float4 a0 = *(const float4*)&aT[k][ty * 8];
            float4 a1 = *(const float4*)&aT[k][ty * 8 + 4];
            float4 bv = *(const float4*)&bl[k][tx * 4];
            float ar[8] = {a0.x, a0.y, a0.z, a0.w, a1.x, a1.y, a1.z, a1.w};
            float bc[4] = {bv.x, bv.y, bv.z, bv.w};
#pragma unroll
            for (int r = 0; r < 8; ++r)
#pragma unroll
                for (int c = 0; c < 4; ++c) acc[r][c] += ar[r] * bc[c];
        }
        __syncthreads();
    }

    float4 bias = *(const float4*)(b1 + n0 + tx * 4);
#pragma unroll
    for (int r = 0; r < 8; ++r) {
        int m = m0 + ty * 8 + r;
        float4 o;
        o.x = acc[r][0] + bias.x; o.y = acc[r][1] + bias.y;
        o.z = acc[r][2] + bias.z; o.w = acc[r][3] + bias.w;
        *(float4*)(X1 + (size_t)m * HID_ + n0 + tx * 4) = o;
    }
}

// ---------------------------------------------------------------------------
// Kernel B: persistent cooperative scan, register-tiled, no h LDS staging.
// 256 blocks x 256 threads. Block b owns cols [4b,4b+4) of Wh1 (h1 outputs)
// and cols [4b,4b+4) of Wi2/Wh2 (h2 outputs). Weights in LDS (float4 per k),
// loaded once. Thread = (g = rows 4g..4g+3, s = k-segment [64s,64s+64)).
// h read straight from global (L2-resident, each element by exactly 1 thread).
// Cross-segment reduce: shfl_xor butterfly over the 16 s-lanes.
// Pipelined: iter i computes h1(i) and h2(i-1); one grid.sync per iter.
// ---------------------------------------------------------------------------
__global__ __launch_bounds__(256, 1) void rnn_scan(
    const float* __restrict__ X1, const float* __restrict__ Wh1,
    const float* __restrict__ Wi2, const float* __restrict__ Wh2,
    const float* __restrict__ b2, float* __restrict__ hb)
{
    cg::grid_group grid = cg::this_grid();

    // [segment][k-within-segment] -> float4 of the block's 4 columns.
    // Row stride 65 float4 = 260 words: bank(seg) = 4*seg % 32 -> only the
    // free 2-way (s vs s+8) aliasing on the 16-lane segment read.
    __shared__ float4 w1[16][65];
    __shared__ float4 w2[16][65];
    __shared__ float4 w3[16][65];

    const int tid = threadIdx.x;
    const int c0  = blockIdx.x * 4;

    for (int k = tid; k < HID_; k += 256) {
        int sg = k >> 6, kk = k & 63;
        w1[sg][kk] = *(const float4*)(Wh1 + (size_t)k * HID_ + c0);
        w2[sg][kk] = *(const float4*)(Wi2 + (size_t)k * HID_ + c0);
        w3[sg][kk] = *(const float4*)(Wh2 + (size_t)k * HID_ + c0);
    }

    const int g = tid >> 4;      // row group: rows 4g..4g+3
    const int s = tid & 15;      // k-segment: k in [64s, 64s+64)
    const float4 b2v = *(const float4*)(b2 + c0);

    float* h1buf[2] = { hb, hb + 65536 };
    float* h2buf[2] = { hb + 131072, hb + 196608 };

    __syncthreads();

    const float4* w1s = &w1[s][0];
    const float4* w2s = &w2[s][0];
    const float4* w3s = &w3[s][0];

    for (int i = 0; i <= S_; ++i) {
        const float* h1p = h1buf[(i + 1) & 1] + s * 64;   // h1(i-1)
        const float* h2p = h2buf[i & 1] + s * 64;         // h2(i-2)

        float acc1[4][4], acc2[4][4];
#pragma unroll
        for (int r = 0; r < 4; ++r)
#pragma unroll
            for (int c = 0; c < 4; ++c) { acc1[r][c] = 0.f; acc2[r][c] = 0.f; }

#pragma unroll 4
        for (int kq = 0; kq < 64; kq += 4) {
            float4 h1v[4], h2v[4];
#pragma unroll
            for (int r = 0; r < 4; ++r) {
                h1v[r] = *(const float4*)(h1p + (g * 4 + r) * HID_ + kq);
                h2v[r] = *(const float4*)(h2p + (g * 4 + r) * HID_ + kq);
            }
#pragma unroll
            for (int j = 0; j < 4; ++j) {
                float4 wa = w1s[kq + j];
                float4 wb = w2s[kq + j];
                float4 wc = w3s[kq + j];
#pragma unroll
                for (int r = 0; r < 4; ++r) {
                    float hx = (j == 0) ? h1v[r].x : (j == 1) ? h1v[r].y
                             : (j == 2) ? h1v[r].z : h1v[r].w;
                    float hy = (j == 0) ? h2v[r].x : (j == 1) ? h2v[r].y
                             : (j == 2) ? h2v[r].z : h2v[r].w;
                    acc1[r][0] += hx * wa.x; acc1[r][1] += hx * wa.y;
                    acc1[r][2] += hx * wa.z; acc1[r][3] += hx * wa.w;
                    acc2[r][0] += hx * wb.x + hy * wc.x;
                    acc2[r][1] += hx * wb.y + hy * wc.y;
                    acc2[r][2] += hx * wb.z + hy * wc.z;
                    acc2[r][3] += hx * wb.w + hy * wc.w;
                }
            }
        }

        // reduce across the 16 k-segments (lanes differing in s)
#pragma unroll
        for (int m = 1; m <= 8; m <<= 1) {
#pragma unroll
            for (int r = 0; r < 4; ++r)
#pragma unroll
                for (int c = 0; c < 4; ++c) {
                    acc1[r][c] += __shfl_xor(acc1[r][c], m, 64);
                    acc2[r][c] += __shfl_xor(acc2[r][c], m, 64);
                }
        }

        if (s == 0) {
#pragma unroll
            for (int r = 0; r < 4; ++r) {
                int row = g * 4 + r;
                if (i < S_) {
                    float4 xv = *(const float4*)(X1 + ((size_t)i * B_ + row) * HID_ + c0);
                    float4 o;
                    o.x = tanhf(xv.x + acc1[r][0]);
                    o.y = tanhf(xv.y + acc1[r][1]);
                    o.z = tanhf(xv.z + acc1[r][2]);
                    o.w = tanhf(xv.w + acc1[r][3]);
                    *(float4*)(h1buf[i & 1] + row * HID_ + c0) = o;
                }
                if (i >= 1) {
                    float4 o;
                    o.x = tanhf(acc2[r][0] + b2v.x);
                    o.y = tanhf(acc2[r][1] + b2v.y);
                    o.z = tanhf(acc2[r][2] + b2v.z);
                    o.w = tanhf(acc2[r][3] + b2v.w);
                    *(float4*)(h2buf[(i + 1) & 1] + row * HID_ + c0) = o;
                }
            }
        }
        if (i < S_) grid.sync();
    }
    // h2(S-1) sits in h2buf[1] (= hb + 196608)
}

// ---------------------------------------------------------------------------
// Kernel C: out[b] = sigmoid(h2_last[b,:] @ Wd + bd)
// ---------------------------------------------------------------------------
__global__ void dense_sigmoid(const float* __restrict__ h2,
                              const float* __restrict__ Wd,
                              const float* __restrict__ bd,
                              float* __restrict__ out)
{
    int b = blockIdx.x, lane = threadIdx.x;   // 64 threads
    float s = 0.f;
    for (int j = lane; j < HID_; j += 64) s += h2[b * HID_ + j] * Wd[j];
#pragma unroll
    for (int off = 32; off > 0; off >>= 1) s += __shfl_down(s, off, 64);
    if (lane == 0) out[b] = 1.f / (1.f + expf(-(s + bd[0])));
}

// ---------------------------------------------------------------------------
extern "C" void kernel_launch(void* const* d_in, const int* in_sizes, int n_in,
                              void* d_out, int out_size, void* d_ws, size_t ws_size,
                              hipStream_t stream)
{
    const int*   x   = (const int*)  d_in[0];
    const float* emb = (const float*)d_in[1];
    const float* Wi1 = (const float*)d_in[2];
    const float* Wh1 = (const float*)d_in[3];
    const float* b1  = (const float*)d_in[4];
    const float* Wi2 = (const float*)d_in[5];
    const float* Wh2 = (const float*)d_in[6];
    const float* b2  = (const float*)d_in[7];
    const float* Wd  = (const float*)d_in[8];
    const float* bd  = (const float*)d_in[9];
    float* out = (float*)d_out;

    // ws layout: X1 (S*B*HID fp32 = 134.2 MB) | 4 h buffers (4*64*1024 fp32)
    float* X1 = (float*)d_ws;
    float* hb = X1 + (size_t)S_ * B_ * HID_;

    hipMemsetAsync(hb, 0, 4 * 65536 * sizeof(float), stream);

    dim3 gA(HID_ / 64, (S_ * B_) / 128);
    embed_gemm<<<gA, dim3(256), 0, stream>>>(x, emb, Wi1, b1, X1);

    const float* X1c = X1;
    void* args[] = { (void*)&X1c, (void*)&Wh1, (void*)&Wi2,
                     (void*)&Wh2, (void*)&b2, (void*)&hb };
    hipLaunchCooperativeKernel((const void*)rnn_scan, dim3(256), dim3(256),
                               args, 0, stream);

    dense_sigmoid<<<64, 64, 0, stream>>>(hb + 196608, Wd, bd, out);
}

// Round 3
// 33570.505 us; speedup vs baseline: 1.1268x; 1.0305x over previous
//
#include <hip/hip_runtime.h>

#define B_   64
#define S_   512
#define EMB_ 512
#define HID_ 1024
#define NBLK_ 256

// ---------------------------------------------------------------------------
// Kernel A: X1[t][b][n] = emb[x[b][t]][:] @ Wi1[:,n] + b1[n]
// M = S*B = 32768 rows (m = t*64 + b), N = 1024, K = 512.
// ---------------------------------------------------------------------------
__global__ __launch_bounds__(256) void embed_gemm(
    const int* __restrict__ x, const float* __restrict__ emb,
    const float* __restrict__ Wi1, const float* __restrict__ b1,
    float* __restrict__ X1)
{
    __shared__ int   tok[128];
    __shared__ float aT[32][132];   // [k][row], +4 pad
    __shared__ float bl[32][68];    // [k][col], +4 pad

    const int tid = threadIdx.x;
    const int m0  = blockIdx.y * 128;
    const int n0  = blockIdx.x * 64;

    if (tid < 128) {
        int m = m0 + tid;
        tok[tid] = x[(m & 63) * S_ + (m >> 6)];   // x[b][t]
    }
    __syncthreads();

    const int tx = tid & 15;   // col group: cols n0 + tx*4 .. +3
    const int ty = tid >> 4;   // row group: rows m0 + ty*8 .. +7

    float acc[8][4];
#pragma unroll
    for (int r = 0; r < 8; ++r)
#pragma unroll
        for (int c = 0; c < 4; ++c) acc[r][c] = 0.f;

    for (int kt = 0; kt < EMB_; kt += 32) {
#pragma unroll
        for (int j = 0; j < 4; ++j) {
            int idx = tid + j * 256;            // 0..1023
            int r   = idx >> 3;
            int k4  = (idx & 7) * 4;
            float4 v = *(const float4*)(emb + (size_t)tok[r] * EMB_ + kt + k4);
            aT[k4 + 0][r] = v.x; aT[k4 + 1][r] = v.y;
            aT[k4 + 2][r] = v.z; aT[k4 + 3][r] = v.w;
        }
#pragma unroll
        for (int j = 0; j < 2; ++j) {
            int idx = tid + j * 256;            // 0..511
            int k   = idx >> 4;
            int c4  = (idx & 15) * 4;
            *(float4*)&bl[k][c4] =
                *(const float4*)(Wi1 + (size_t)(kt + k) * HID_ + n0 + c4);
        }
        __syncthreads();

#pragma unroll 4
        for (int k = 0; k < 32; ++k) {
            float4 a0 = *(const float4*)&aT[k][ty * 8];
            float4 a1 = *(const float4*)&aT[k][ty * 8 + 4];
            float4 bv = *(const float4*)&bl[k][tx * 4];
            float ar[8] = {a0.x, a0.y, a0.z, a0.w, a1.x, a1.y, a1.z, a1.w};
            float bc[4] = {bv.x, bv.y, bv.z, bv.w};
#pragma unroll
            for (int r = 0; r < 8; ++r)
#pragma unroll
                for (int c = 0; c < 4; ++c) acc[r][c] += ar[r] * bc[c];
        }
        __syncthreads();
    }

    float4 bias = *(const float4*)(b1 + n0 + tx * 4);
#pragma unroll
    for (int r = 0; r < 8; ++r) {
        int m = m0 + ty * 8 + r;
        float4 o;
        o.x = acc[r][0] + bias.x; o.y = acc[r][1] + bias.y;
        o.z = acc[r][2] + bias.z; o.w = acc[r][3] + bias.w;
        *(float4*)(X1 + (size_t)m * HID_ + n0 + tx * 4) = o;
    }
}

// ---------------------------------------------------------------------------
// Kernel B: persistent scan. Identical compute to round 2; the ONLY change is
// the barrier: custom per-step arrival-counter barrier (agent-scope atomics)
// + one-sided agent fences, instead of cg::grid_group::sync().
// cnt[] lives in ws, zeroed by the in-graph memset each launch (replay-safe,
// no reset race: one counter per step).
// ---------------------------------------------------------------------------
__global__ __launch_bounds__(256, 1) void rnn_scan(
    const float* __restrict__ X1, const float* __restrict__ Wh1,
    const float* __restrict__ Wi2, const float* __restrict__ Wh2,
    const float* __restrict__ b2, float* __restrict__ hb,
    unsigned int* __restrict__ cnt)
{
    // [segment][k-within-segment] -> float4 of the block's 4 columns.
    __shared__ float4 w1[16][65];
    __shared__ float4 w2[16][65];
    __shared__ float4 w3[16][65];

    const int tid = threadIdx.x;
    const int c0  = blockIdx.x * 4;

    for (int k = tid; k < HID_; k += 256) {
        int sg = k >> 6, kk = k & 63;
        w1[sg][kk] = *(const float4*)(Wh1 + (size_t)k * HID_ + c0);
        w2[sg][kk] = *(const float4*)(Wi2 + (size_t)k * HID_ + c0);
        w3[sg][kk] = *(const float4*)(Wh2 + (size_t)k * HID_ + c0);
    }

    const int g = tid >> 4;      // row group: rows 4g..4g+3
    const int s = tid & 15;      // k-segment: k in [64s, 64s+64)
    const float4 b2v = *(const float4*)(b2 + c0);

    float* h1buf[2] = { hb, hb + 65536 };
    float* h2buf[2] = { hb + 131072, hb + 196608 };

    __syncthreads();

    const float4* w1s = &w1[s][0];
    const float4* w2s = &w2[s][0];
    const float4* w3s = &w3[s][0];

    for (int i = 0; i <= S_; ++i) {
        const float* h1p = h1buf[(i + 1) & 1] + s * 64;   // h1(i-1)
        const float* h2p = h2buf[i & 1] + s * 64;         // h2(i-2)

        float acc1[4][4], acc2[4][4];
#pragma unroll
        for (int r = 0; r < 4; ++r)
#pragma unroll
            for (int c = 0; c < 4; ++c) { acc1[r][c] = 0.f; acc2[r][c] = 0.f; }

#pragma unroll 4
        for (int kq = 0; kq < 64; kq += 4) {
            float4 h1v[4], h2v[4];
#pragma unroll
            for (int r = 0; r < 4; ++r) {
                h1v[r] = *(const float4*)(h1p + (g * 4 + r) * HID_ + kq);
                h2v[r] = *(const float4*)(h2p + (g * 4 + r) * HID_ + kq);
            }
#pragma unroll
            for (int j = 0; j < 4; ++j) {
                float4 wa = w1s[kq + j];
                float4 wb = w2s[kq + j];
                float4 wc = w3s[kq + j];
#pragma unroll
                for (int r = 0; r < 4; ++r) {
                    float hx = (j == 0) ? h1v[r].x : (j == 1) ? h1v[r].y
                             : (j == 2) ? h1v[r].z : h1v[r].w;
                    float hy = (j == 0) ? h2v[r].x : (j == 1) ? h2v[r].y
                             : (j == 2) ? h2v[r].z : h2v[r].w;
                    acc1[r][0] += hx * wa.x; acc1[r][1] += hx * wa.y;
                    acc1[r][2] += hx * wa.z; acc1[r][3] += hx * wa.w;
                    acc2[r][0] += hx * wb.x + hy * wc.x;
                    acc2[r][1] += hx * wb.y + hy * wc.y;
                    acc2[r][2] += hx * wb.z + hy * wc.z;
                    acc2[r][3] += hx * wb.w + hy * wc.w;
                }
            }
        }

        // reduce across the 16 k-segments (lanes differing in s)
#pragma unroll
        for (int m = 1; m <= 8; m <<= 1) {
#pragma unroll
            for (int r = 0; r < 4; ++r)
#pragma unroll
                for (int c = 0; c < 4; ++c) {
                    acc1[r][c] += __shfl_xor(acc1[r][c], m, 64);
                    acc2[r][c] += __shfl_xor(acc2[r][c], m, 64);
                }
        }

        if (s == 0) {
#pragma unroll
            for (int r = 0; r < 4; ++r) {
                int row = g * 4 + r;
                if (i < S_) {
                    float4 xv = *(const float4*)(X1 + ((size_t)i * B_ + row) * HID_ + c0);
                    float4 o;
                    o.x = tanhf(xv.x + acc1[r][0]);
                    o.y = tanhf(xv.y + acc1[r][1]);
                    o.z = tanhf(xv.z + acc1[r][2]);
                    o.w = tanhf(xv.w + acc1[r][3]);
                    *(float4*)(h1buf[i & 1] + row * HID_ + c0) = o;
                }
                if (i >= 1) {
                    float4 o;
                    o.x = tanhf(acc2[r][0] + b2v.x);
                    o.y = tanhf(acc2[r][1] + b2v.y);
                    o.z = tanhf(acc2[r][2] + b2v.z);
                    o.w = tanhf(acc2[r][3] + b2v.w);
                    *(float4*)(h2buf[(i + 1) & 1] + row * HID_ + c0) = o;
                }
            }
        }

        if (i < S_) {
            // -------- custom grid barrier (replaces cg grid.sync) --------
            __syncthreads();  // all waves' h stores issued & drained (vmcnt0)
            __builtin_amdgcn_fence(__ATOMIC_RELEASE, "agent");  // flush dirty h to coherent point
            if (tid == 0) {
                __hip_atomic_fetch_add(&cnt[i], 1u, __ATOMIC_RELAXED,
                                       __HIP_MEMORY_SCOPE_AGENT);
                while (__hip_atomic_load(&cnt[i], __ATOMIC_RELAXED,
                                         __HIP_MEMORY_SCOPE_AGENT) < NBLK_) {
                    __builtin_amdgcn_s_sleep(2);
                }
            }
            __syncthreads();
            __builtin_amdgcn_fence(__ATOMIC_ACQUIRE, "agent"); // invalidate stale L1/L2
            // -------------------------------------------------------------
        }
    }
    // h2(S-1) sits in h2buf[1] (= hb + 196608)
}

// ---------------------------------------------------------------------------
// Kernel C: out[b] = sigmoid(h2_last[b,:] @ Wd + bd)
// ---------------------------------------------------------------------------
__global__ void dense_sigmoid(const float* __restrict__ h2,
                              const float* __restrict__ Wd,
                              const float* __restrict__ bd,
                              float* __restrict__ out)
{
    int b = blockIdx.x, lane = threadIdx.x;   // 64 threads
    float s = 0.f;
    for (int j = lane; j < HID_; j += 64) s += h2[b * HID_ + j] * Wd[j];
#pragma unroll
    for (int off = 32; off > 0; off >>= 1) s += __shfl_down(s, off, 64);
    if (lane == 0) out[b] = 1.f / (1.f + expf(-(s + bd[0])));
}

// ---------------------------------------------------------------------------
extern "C" void kernel_launch(void* const* d_in, const int* in_sizes, int n_in,
                              void* d_out, int out_size, void* d_ws, size_t ws_size,
                              hipStream_t stream)
{
    const int*   x   = (const int*)  d_in[0];
    const float* emb = (const float*)d_in[1];
    const float* Wi1 = (const float*)d_in[2];
    const float* Wh1 = (const float*)d_in[3];
    const float* b1  = (const float*)d_in[4];
    const float* Wi2 = (const float*)d_in[5];
    const float* Wh2 = (const float*)d_in[6];
    const float* b2  = (const float*)d_in[7];
    const float* Wd  = (const float*)d_in[8];
    const float* bd  = (const float*)d_in[9];
    float* out = (float*)d_out;

    // ws layout: X1 (S*B*HID fp32 = 134.2 MB) | 4 h buffers (1 MB) | 512 cnt
    float* X1 = (float*)d_ws;
    float* hb = X1 + (size_t)S_ * B_ * HID_;
    unsigned int* cnt = (unsigned int*)(hb + 4 * 65536);

    // zero h buffers + barrier counters (contiguous); in-graph -> replay-safe
    hipMemsetAsync(hb, 0, 4 * 65536 * sizeof(float) + S_ * sizeof(unsigned int),
                   stream);

    dim3 gA(HID_ / 64, (S_ * B_) / 128);
    embed_gemm<<<gA, dim3(256), 0, stream>>>(x, emb, Wi1, b1, X1);

    const float* X1c = X1;
    void* args[] = { (void*)&X1c, (void*)&Wh1, (void*)&Wi2,
                     (void*)&Wh2, (void*)&b2, (void*)&hb, (void*)&cnt };
    hipLaunchCooperativeKernel((const void*)rnn_scan, dim3(NBLK_), dim3(256),
                               args, 0, stream);

    dense_sigmoid<<<64, 64, 0, stream>>>(hb + 196608, Wd, bd, out);
}

// Round 5
// 23401.715 us; speedup vs baseline: 1.6165x; 1.4345x over previous
//
#include <hip/hip_runtime.h>

#define B_   64
#define S_   512
#define EMB_ 512
#define HID_ 1024
#define NBLK_ 256

// Native vector type usable in inline-asm "v" constraints (HIP float4 is a
// struct and cannot bind to register constraints).
typedef float f32x4 __attribute__((ext_vector_type(4)));

// ---------------------------------------------------------------------------
// Coherent (Infinity-Cache) access helpers: sc0 sc1 bypasses L1+L2 so no
// cache-wide fences are needed for cross-XCD h exchange.
// ---------------------------------------------------------------------------
__device__ __forceinline__ f32x4 ld_coh(const float* p) {
    f32x4 d;
    asm volatile("global_load_dwordx4 %0, %1, off sc0 sc1"
                 : "=v"(d) : "v"(p));
    return d;
}
__device__ __forceinline__ void st_coh(float* p, f32x4 v) {
    asm volatile("global_store_dwordx4 %0, %1, off sc0 sc1"
                 :: "v"(p), "v"(v) : "memory");
}

// ---------------------------------------------------------------------------
// Kernel A: X1[t][b][n] = emb[x[b][t]][:] @ Wi1[:,n] + b1[n]
// ---------------------------------------------------------------------------
__global__ __launch_bounds__(256) void embed_gemm(
    const int* __restrict__ x, const float* __restrict__ emb,
    const float* __restrict__ Wi1, const float* __restrict__ b1,
    float* __restrict__ X1)
{
    __shared__ int   tok[128];
    __shared__ float aT[32][132];
    __shared__ float bl[32][68];

    const int tid = threadIdx.x;
    const int m0  = blockIdx.y * 128;
    const int n0  = blockIdx.x * 64;

    if (tid < 128) {
        int m = m0 + tid;
        tok[tid] = x[(m & 63) * S_ + (m >> 6)];
    }
    __syncthreads();

    const int tx = tid & 15;
    const int ty = tid >> 4;

    float acc[8][4];
#pragma unroll
    for (int r = 0; r < 8; ++r)
#pragma unroll
        for (int c = 0; c < 4; ++c) acc[r][c] = 0.f;

    for (int kt = 0; kt < EMB_; kt += 32) {
#pragma unroll
        for (int j = 0; j < 4; ++j) {
            int idx = tid + j * 256;
            int r   = idx >> 3;
            int k4  = (idx & 7) * 4;
            float4 v = *(const float4*)(emb + (size_t)tok[r] * EMB_ + kt + k4);
            aT[k4 + 0][r] = v.x; aT[k4 + 1][r] = v.y;
            aT[k4 + 2][r] = v.z; aT[k4 + 3][r] = v.w;
        }
#pragma unroll
        for (int j = 0; j < 2; ++j) {
            int idx = tid + j * 256;
            int k   = idx >> 4;
            int c4  = (idx & 15) * 4;
            *(float4*)&bl[k][c4] =
                *(const float4*)(Wi1 + (size_t)(kt + k) * HID_ + n0 + c4);
        }
        __syncthreads();

#pragma unroll 4
        for (int k = 0; k < 32; ++k) {
            float4 a0 = *(const float4*)&aT[k][ty * 8];
            float4 a1 = *(const float4*)&aT[k][ty * 8 + 4];
            float4 bv = *(const float4*)&bl[k][tx * 4];
            float ar[8] = {a0.x, a0.y, a0.z, a0.w, a1.x, a1.y, a1.z, a1.w};
            float bc[4] = {bv.x, bv.y, bv.z, bv.w};
#pragma unroll
            for (int r = 0; r < 8; ++r)
#pragma unroll
                for (int c = 0; c < 4; ++c) acc[r][c] += ar[r] * bc[c];
        }
        __syncthreads();
    }

    float4 bias = *(const float4*)(b1 + n0 + tx * 4);
#pragma unroll
    for (int r = 0; r < 8; ++r) {
        int m = m0 + ty * 8 + r;
        float4 o;
        o.x = acc[r][0] + bias.x; o.y = acc[r][1] + bias.y;
        o.z = acc[r][2] + bias.z; o.w = acc[r][3] + bias.w;
        *(float4*)(X1 + (size_t)m * HID_ + n0 + tx * 4) = o;
    }
}

// ---------------------------------------------------------------------------
// Kernel B: persistent scan. Same decomposition/compute as round 2/3.
// h exchange via sc0|sc1 coherent loads/stores (IC-coherent, no cache-wide
// fences anywhere); pipelined 8-load batches with counted vmcnt ping-pong;
// fence-free arrival-counter barrier.
// ---------------------------------------------------------------------------
__global__ __launch_bounds__(256, 1) void rnn_scan(
    const float* __restrict__ X1, const float* __restrict__ Wh1,
    const float* __restrict__ Wi2, const float* __restrict__ Wh2,
    const float* __restrict__ b2, float* __restrict__ hb,
    unsigned int* __restrict__ cnt)
{
    __shared__ float4 w1[16][65];
    __shared__ float4 w2[16][65];
    __shared__ float4 w3[16][65];

    const int tid = threadIdx.x;
    const int c0  = blockIdx.x * 4;

    for (int k = tid; k < HID_; k += 256) {
        int sg = k >> 6, kk = k & 63;
        w1[sg][kk] = *(const float4*)(Wh1 + (size_t)k * HID_ + c0);
        w2[sg][kk] = *(const float4*)(Wi2 + (size_t)k * HID_ + c0);
        w3[sg][kk] = *(const float4*)(Wh2 + (size_t)k * HID_ + c0);
    }

    const int g = tid >> 4;      // row group: rows 4g..4g+3
    const int s = tid & 15;      // k-segment: k in [64s, 64s+64)
    const float4 b2v = *(const float4*)(b2 + c0);

    float* h1buf[2] = { hb, hb + 65536 };
    float* h2buf[2] = { hb + 131072, hb + 196608 };

    __syncthreads();

    const float4* w1s = &w1[s][0];
    const float4* w2s = &w2[s][0];
    const float4* w3s = &w3[s][0];

    for (int i = 0; i <= S_; ++i) {
        const float* h1p = h1buf[(i + 1) & 1] + s * 64;   // h1(i-1)
        const float* h2p = h2buf[i & 1] + s * 64;         // h2(i-2)

        const float* r1[4];
        const float* r2[4];
#pragma unroll
        for (int r = 0; r < 4; ++r) {
            r1[r] = h1p + (g * 4 + r) * HID_;
            r2[r] = h2p + (g * 4 + r) * HID_;
        }

        float acc1[4][4], acc2[4][4];
#pragma unroll
        for (int r = 0; r < 4; ++r)
#pragma unroll
            for (int c = 0; c < 4; ++c) { acc1[r][c] = 0.f; acc2[r][c] = 0.f; }

        f32x4 A1[4], A2[4], B1[4], B2[4];

        // prologue: issue batch 0 (kq=0) into A
#pragma unroll
        for (int r = 0; r < 4; ++r) {
            A1[r] = ld_coh(r1[r] + 0);
            A2[r] = ld_coh(r2[r] + 0);
        }

#pragma unroll
        for (int it = 0; it < 16; ++it) {
            const int kq = it * 4;
            if (it < 15) {
                const int kqn = (it + 1) * 4;
                if (it & 1) {
#pragma unroll
                    for (int r = 0; r < 4; ++r) {
                        A1[r] = ld_coh(r1[r] + kqn);
                        A2[r] = ld_coh(r2[r] + kqn);
                    }
                } else {
#pragma unroll
                    for (int r = 0; r < 4; ++r) {
                        B1[r] = ld_coh(r1[r] + kqn);
                        B2[r] = ld_coh(r2[r] + kqn);
                    }
                }
            }
            if (it < 15) asm volatile("s_waitcnt vmcnt(8)" ::: "memory");
            else         asm volatile("s_waitcnt vmcnt(0)" ::: "memory");
            __builtin_amdgcn_sched_barrier(0);

            const f32x4* c1 = (it & 1) ? B1 : A1;
            const f32x4* c2 = (it & 1) ? B2 : A2;

#pragma unroll
            for (int j = 0; j < 4; ++j) {
                float4 wa = w1s[kq + j];
                float4 wb = w2s[kq + j];
                float4 wc = w3s[kq + j];
#pragma unroll
                for (int r = 0; r < 4; ++r) {
                    float hx = c1[r][j];
                    float hy = c2[r][j];
                    acc1[r][0] += hx * wa.x; acc1[r][1] += hx * wa.y;
                    acc1[r][2] += hx * wa.z; acc1[r][3] += hx * wa.w;
                    acc2[r][0] += hx * wb.x + hy * wc.x;
                    acc2[r][1] += hx * wb.y + hy * wc.y;
                    acc2[r][2] += hx * wb.z + hy * wc.z;
                    acc2[r][3] += hx * wb.w + hy * wc.w;
                }
            }
        }

        // reduce across the 16 k-segments
#pragma unroll
        for (int m = 1; m <= 8; m <<= 1) {
#pragma unroll
            for (int r = 0; r < 4; ++r)
#pragma unroll
                for (int c = 0; c < 4; ++c) {
                    acc1[r][c] += __shfl_xor(acc1[r][c], m, 64);
                    acc2[r][c] += __shfl_xor(acc2[r][c], m, 64);
                }
        }

        if (s == 0) {
#pragma unroll
            for (int r = 0; r < 4; ++r) {
                int row = g * 4 + r;
                if (i < S_) {
                    float4 xv = *(const float4*)(X1 + ((size_t)i * B_ + row) * HID_ + c0);
                    f32x4 o;
                    o.x = tanhf(xv.x + acc1[r][0]);
                    o.y = tanhf(xv.y + acc1[r][1]);
                    o.z = tanhf(xv.z + acc1[r][2]);
                    o.w = tanhf(xv.w + acc1[r][3]);
                    st_coh(h1buf[i & 1] + row * HID_ + c0, o);
                }
                if (i >= 1) {
                    f32x4 o;
                    o.x = tanhf(acc2[r][0] + b2v.x);
                    o.y = tanhf(acc2[r][1] + b2v.y);
                    o.z = tanhf(acc2[r][2] + b2v.z);
                    o.w = tanhf(acc2[r][3] + b2v.w);
                    st_coh(h2buf[(i + 1) & 1] + row * HID_ + c0, o);
                }
            }
        }

        if (i < S_) {
            // ---- fence-free barrier: drain own stores, arrive, poll ----
            asm volatile("s_waitcnt vmcnt(0)" ::: "memory"); // own stores at IC
            __syncthreads();                                 // all waves drained
            if (tid == 0) {
                __hip_atomic_fetch_add(&cnt[i], 1u, __ATOMIC_RELAXED,
                                       __HIP_MEMORY_SCOPE_AGENT);
                while (__hip_atomic_load(&cnt[i], __ATOMIC_RELAXED,
                                         __HIP_MEMORY_SCOPE_AGENT) < NBLK_) {
                    __builtin_amdgcn_s_sleep(1);
                }
            }
            __syncthreads();
            // ------------------------------------------------------------
        }
    }
    // h2(S-1) sits in h2buf[1] (= hb + 196608)
}

// ---------------------------------------------------------------------------
// Kernel C: out[b] = sigmoid(h2_last[b,:] @ Wd + bd)
// ---------------------------------------------------------------------------
__global__ void dense_sigmoid(const float* __restrict__ h2,
                              const float* __restrict__ Wd,
                              const float* __restrict__ bd,
                              float* __restrict__ out)
{
    int b = blockIdx.x, lane = threadIdx.x;
    float s = 0.f;
    for (int j = lane; j < HID_; j += 64) s += h2[b * HID_ + j] * Wd[j];
#pragma unroll
    for (int off = 32; off > 0; off >>= 1) s += __shfl_down(s, off, 64);
    if (lane == 0) out[b] = 1.f / (1.f + expf(-(s + bd[0])));
}

// ---------------------------------------------------------------------------
extern "C" void kernel_launch(void* const* d_in, const int* in_sizes, int n_in,
                              void* d_out, int out_size, void* d_ws, size_t ws_size,
                              hipStream_t stream)
{
    const int*   x   = (const int*)  d_in[0];
    const float* emb = (const float*)d_in[1];
    const float* Wi1 = (const float*)d_in[2];
    const float* Wh1 = (const float*)d_in[3];
    const float* b1  = (const float*)d_in[4];
    const float* Wi2 = (const float*)d_in[5];
    const float* Wh2 = (const float*)d_in[6];
    const float* b2  = (const float*)d_in[7];
    const float* Wd  = (const float*)d_in[8];
    const float* bd  = (const float*)d_in[9];
    float* out = (float*)d_out;

    float* X1 = (float*)d_ws;
    float* hb = X1 + (size_t)S_ * B_ * HID_;
    unsigned int* cnt = (unsigned int*)(hb + 4 * 65536);

    hipMemsetAsync(hb, 0, 4 * 65536 * sizeof(float) + S_ * sizeof(unsigned int),
                   stream);

    dim3 gA(HID_ / 64, (S_ * B_) / 128);
    embed_gemm<<<gA, dim3(256), 0, stream>>>(x, emb, Wi1, b1, X1);

    const float* X1c = X1;
    void* args[] = { (void*)&X1c, (void*)&Wh1, (void*)&Wi2,
                     (void*)&Wh2, (void*)&b2, (void*)&hb, (void*)&cnt };
    hipLaunchCooperativeKernel((const void*)rnn_scan, dim3(NBLK_), dim3(256),
                               args, 0, stream);

    dense_sigmoid<<<64, 64, 0, stream>>>(hb + 196608, Wd, bd, out);
}

// Round 8
// 18383.315 us; speedup vs baseline: 2.0578x; 1.2730x over previous
//
#include <hip/hip_runtime.h>

#define B_   64
#define S_   512
#define EMB_ 512
#define HID_ 1024
#define NBLK_ 256

typedef float f32x4 __attribute__((ext_vector_type(4)));

// Coherent (Infinity-Cache) access: sc0 sc1 bypasses L1+L2 -> no cache-wide
// fences needed for cross-XCD exchange. Proven in R5.
__device__ __forceinline__ f32x4 ld_coh4(const float* p) {
    f32x4 d;
    asm volatile("global_load_dwordx4 %0, %1, off sc0 sc1" : "=v"(d) : "v"(p));
    return d;
}
__device__ __forceinline__ float ld_coh1(const float* p) {
    float d;
    asm volatile("global_load_dword %0, %1, off sc0 sc1" : "=v"(d) : "v"(p));
    return d;
}
__device__ __forceinline__ void st_coh4(float* p, f32x4 v) {
    asm volatile("global_store_dwordx4 %0, %1, off sc0 sc1" :: "v"(p), "v"(v) : "memory");
}
__device__ __forceinline__ void st_coh1(float* p, float v) {
    asm volatile("global_store_dword %0, %1, off sc0 sc1" :: "v"(p), "v"(v) : "memory");
}

// ---------------------------------------------------------------------------
// Persistent split-k scan. 256 blocks x 256 threads.
// Block (kg = bk>>5, cg = bk&31):
//   phase A: stage h1(i-1)/h2(i-2) k-slice [64 rows][128 k] via IC loads into
//     LDS, gather emb[x[:,i]] x-slice [64][64] (plain cached), compute partial
//     sums for its 32 cols over its k-slice (incl. x@Wi1 part), st_coh to
//     p1/p2[kg]. Barrier A.
//   phase B: block bk reduces the 8 kg-partials for cols [4bk,4bk+4),
//     adds bias, tanh, st_coh h1(i)/h2(i-1). Barrier B.
// Pipelined like R2: iteration i produces h1(i) and h2(i-1).
// ---------------------------------------------------------------------------
__global__ __launch_bounds__(256, 1) void rnn_scan(
    const int* __restrict__ x, const float* __restrict__ emb,
    const float* __restrict__ Wi1, const float* __restrict__ Wh1,
    const float* __restrict__ b1,  const float* __restrict__ Wi2,
    const float* __restrict__ Wh2, const float* __restrict__ b2,
    float* __restrict__ hb, float* __restrict__ p1, float* __restrict__ p2,
    unsigned int* __restrict__ cntA, unsigned int* __restrict__ cntB)
{
    __shared__ float w1s[128 * 32];   // Wh1 slice [k][c]
    __shared__ float w2s[128 * 32];   // Wi2 slice
    __shared__ float w3s[128 * 32];   // Wh2 slice
    __shared__ float wxs[64 * 32];    // Wi1 slice [kx][c]
    __shared__ float h1s[64 * 132];   // h1 k-slice, padded stride
    __shared__ float h2s[64 * 132];
    __shared__ float xs [64 * 68];    // emb k-slice, padded stride
    __shared__ int   toks[64];

    const int tid = threadIdx.x;
    const int bk  = blockIdx.x;
    const int kg  = bk >> 5;          // 0..7   k-group
    const int cg  = bk & 31;          // 0..31  col-group (32 cols)
    const int k0  = kg * 128;         // h-k slice base (HID)
    const int kx0 = kg * 64;          // x-k slice base (EMB)
    const int cs0 = cg * 32;          // col-slice base

    // ---- stage weight slices (once) ----
    for (int idx = tid; idx < 1024; idx += 256) {        // 128*32 /4
        int k = idx >> 3, c4 = (idx & 7) * 4;
        *(f32x4*)&w1s[k * 32 + c4] = *(const f32x4*)(Wh1 + (size_t)(k0 + k) * HID_ + cs0 + c4);
        *(f32x4*)&w2s[k * 32 + c4] = *(const f32x4*)(Wi2 + (size_t)(k0 + k) * HID_ + cs0 + c4);
        *(f32x4*)&w3s[k * 32 + c4] = *(const f32x4*)(Wh2 + (size_t)(k0 + k) * HID_ + cs0 + c4);
    }
    for (int idx = tid; idx < 512; idx += 256) {         // 64*32 /4
        int k = idx >> 3, c4 = (idx & 7) * 4;
        *(f32x4*)&wxs[k * 32 + c4] = *(const f32x4*)(Wi1 + (size_t)(kx0 + k) * HID_ + cs0 + c4);
    }

    const int row = tid >> 2;         // 0..63 (batch row; also phase-B row)
    const int cq  = tid & 3;          // 0..3
    const int cb  = cq * 8;           // col offset within 32-col slice

    const int c0   = bk * 4;          // phase-B output col base
    const int ocol = c0 + cq;         // phase-B output col
    const float b1v = b1[ocol];
    const float b2v = b2[ocol];

    float* h1buf[2] = { hb, hb + 65536 };
    float* h2buf[2] = { hb + 131072, hb + 196608 };

    __syncthreads();

    for (int i = 0; i <= S_; ++i) {
        const float* h1src = h1buf[(i + 1) & 1];   // h1(i-1)
        const float* h2src = h2buf[i & 1];         // h2(i-2)

        // ---- token ids for this step (dummy at i==S_, result unused) ----
        const int ii = (i < S_) ? i : 0;
        if (tid < 64) toks[tid] = x[tid * S_ + ii];

        // ---- issue h k-slice IC loads ----
        f32x4 va[8], vb[8];
#pragma unroll
        for (int j = 0; j < 8; ++j) {
            int idx = tid + j * 256;           // 0..2047 f32x4 units
            int r   = idx >> 5;                // row
            int kk  = (idx & 31) * 4;          // k within slice
            va[j] = ld_coh4(h1src + r * HID_ + k0 + kk);
            vb[j] = ld_coh4(h2src + r * HID_ + k0 + kk);
        }
        __syncthreads();                        // toks visible
        // ---- gather emb x-slice (plain cached; emb is read-only) ----
        f32x4 xg[4];
        {
            int kk = (tid & 3) * 16;
            const float* ep = emb + (size_t)toks[row] * EMB_ + kx0 + kk;
#pragma unroll
            for (int j = 0; j < 4; ++j) xg[j] = *(const f32x4*)(ep + j * 4);
        }
        asm volatile("s_waitcnt vmcnt(0)" ::: "memory");
        __builtin_amdgcn_sched_barrier(0);
        // ---- write staged data to LDS ----
#pragma unroll
        for (int j = 0; j < 8; ++j) {
            int idx = tid + j * 256;
            int r   = idx >> 5;
            int kk  = (idx & 31) * 4;
            *(f32x4*)&h1s[r * 132 + kk] = va[j];
            *(f32x4*)&h2s[r * 132 + kk] = vb[j];
        }
        {
            int kk = (tid & 3) * 16;
#pragma unroll
            for (int j = 0; j < 4; ++j) *(f32x4*)&xs[row * 68 + kk + j * 4] = xg[j];
        }
        __syncthreads();

        // ---- phase A compute: partials for 8 cols (cb..cb+8) ----
        f32x4 a1lo = {0,0,0,0}, a1hi = {0,0,0,0};
        f32x4 a2lo = {0,0,0,0}, a2hi = {0,0,0,0};

        const float* h1r = &h1s[row * 132];
        const float* h2r = &h2s[row * 132];
#pragma unroll 8
        for (int kq = 0; kq < 128; kq += 4) {
            f32x4 hv1 = *(const f32x4*)(h1r + kq);
            f32x4 hv2 = *(const f32x4*)(h2r + kq);
#pragma unroll
            for (int j = 0; j < 4; ++j) {
                const int k = kq + j;
                f32x4 wa0 = *(const f32x4*)&w1s[k * 32 + cb];
                f32x4 wa1 = *(const f32x4*)&w1s[k * 32 + cb + 4];
                f32x4 wb0 = *(const f32x4*)&w2s[k * 32 + cb];
                f32x4 wb1 = *(const f32x4*)&w2s[k * 32 + cb + 4];
                f32x4 wc0 = *(const f32x4*)&w3s[k * 32 + cb];
                f32x4 wc1 = *(const f32x4*)&w3s[k * 32 + cb + 4];
                float h1x = hv1[j], h2x = hv2[j];
                a1lo += h1x * wa0;  a1hi += h1x * wa1;
                a2lo += h1x * wb0 + h2x * wc0;
                a2hi += h1x * wb1 + h2x * wc1;
            }
        }
        const float* xr = &xs[row * 68];
#pragma unroll 4
        for (int kq = 0; kq < 64; kq += 4) {
            f32x4 xv = *(const f32x4*)(xr + kq);
#pragma unroll
            for (int j = 0; j < 4; ++j) {
                const int k = kq + j;
                f32x4 wx0 = *(const f32x4*)&wxs[k * 32 + cb];
                f32x4 wx1 = *(const f32x4*)&wxs[k * 32 + cb + 4];
                a1lo += xv[j] * wx0;  a1hi += xv[j] * wx1;
            }
        }

        // ---- write partials (IC) ----
        {
            float* pp1 = p1 + ((size_t)kg * 64 + row) * HID_ + cs0 + cb;
            float* pp2 = p2 + ((size_t)kg * 64 + row) * HID_ + cs0 + cb;
            st_coh4(pp1,     a1lo); st_coh4(pp1 + 4, a1hi);
            st_coh4(pp2,     a2lo); st_coh4(pp2 + 4, a2hi);
        }

        // ---- barrier A ----
        asm volatile("s_waitcnt vmcnt(0)" ::: "memory");
        __syncthreads();
        if (tid == 0) {
            __hip_atomic_fetch_add(&cntA[i], 1u, __ATOMIC_RELAXED,
                                   __HIP_MEMORY_SCOPE_AGENT);
            while (__hip_atomic_load(&cntA[i], __ATOMIC_RELAXED,
                                     __HIP_MEMORY_SCOPE_AGENT) < NBLK_)
                __builtin_amdgcn_s_sleep(1);
        }
        __syncthreads();

        // ---- phase B: reduce 8 partials, bias + tanh, write h ----
        float part1[8], part2[8];
#pragma unroll
        for (int g8 = 0; g8 < 8; ++g8) {
            part1[g8] = ld_coh1(p1 + ((size_t)g8 * 64 + row) * HID_ + ocol);
            part2[g8] = ld_coh1(p2 + ((size_t)g8 * 64 + row) * HID_ + ocol);
        }
        asm volatile("s_waitcnt vmcnt(0)" ::: "memory");
        __builtin_amdgcn_sched_barrier(0);
        float s1 = b1v, s2 = b2v;
#pragma unroll
        for (int g8 = 0; g8 < 8; ++g8) { s1 += part1[g8]; s2 += part2[g8]; }

        if (i < S_)
            st_coh1(h1buf[i & 1] + row * HID_ + ocol, tanhf(s1));
        if (i >= 1)
            st_coh1(h2buf[(i + 1) & 1] + row * HID_ + ocol, tanhf(s2));

        if (i < S_) {
            // ---- barrier B ----
            asm volatile("s_waitcnt vmcnt(0)" ::: "memory");
            __syncthreads();
            if (tid == 0) {
                __hip_atomic_fetch_add(&cntB[i], 1u, __ATOMIC_RELAXED,
                                       __HIP_MEMORY_SCOPE_AGENT);
                while (__hip_atomic_load(&cntB[i], __ATOMIC_RELAXED,
                                         __HIP_MEMORY_SCOPE_AGENT) < NBLK_)
                    __builtin_amdgcn_s_sleep(1);
            }
            __syncthreads();
        }
    }
    // h2(S-1) sits in h2buf[1] (= hb + 196608)
}

// ---------------------------------------------------------------------------
// out[b] = sigmoid(h2_last[b,:] @ Wd + bd)
// ---------------------------------------------------------------------------
__global__ void dense_sigmoid(const float* __restrict__ h2,
                              const float* __restrict__ Wd,
                              const float* __restrict__ bd,
                              float* __restrict__ out)
{
    int b = blockIdx.x, lane = threadIdx.x;
    float s = 0.f;
    for (int j = lane; j < HID_; j += 64) s += h2[b * HID_ + j] * Wd[j];
#pragma unroll
    for (int off = 32; off > 0; off >>= 1) s += __shfl_down(s, off, 64);
    if (lane == 0) out[b] = 1.f / (1.f + expf(-(s + bd[0])));
}

// ---------------------------------------------------------------------------
// ws layout (bytes):
//   hb   @ 0          1,048,576  (4 h buffers fp32)
//   cntA @ 1,048,576      4,096  (u32 x513 used)
//   cntB @ 1,052,672      4,096
//   p1   @ 1,056,768  2,097,152  (8 kg x 64 rows x 1024 cols fp32)
//   p2   @ 3,153,920  2,097,152
// total 5,251,072 B.  memset zeroes hb+cntA+cntB = 1,056,768 B.
// (p1/p2 are written before read every step -> no init needed.)
// ---------------------------------------------------------------------------
extern "C" void kernel_launch(void* const* d_in, const int* in_sizes, int n_in,
                              void* d_out, int out_size, void* d_ws, size_t ws_size,
                              hipStream_t stream)
{
    const int*   x   = (const int*)  d_in[0];
    const float* emb = (const float*)d_in[1];
    const float* Wi1 = (const float*)d_in[2];
    const float* Wh1 = (const float*)d_in[3];
    const float* b1  = (const float*)d_in[4];
    const float* Wi2 = (const float*)d_in[5];
    const float* Wh2 = (const float*)d_in[6];
    const float* b2  = (const float*)d_in[7];
    const float* Wd  = (const float*)d_in[8];
    const float* bd  = (const float*)d_in[9];
    float* out = (float*)d_out;

    char* w = (char*)d_ws;
    float*        hb   = (float*)w;
    unsigned int* cntA = (unsigned int*)(w + 1048576);
    unsigned int* cntB = (unsigned int*)(w + 1052672);
    float*        p1   = (float*)(w + 1056768);
    float*        p2   = (float*)(w + 3153920);

    hipMemsetAsync(w, 0, 1056768, stream);

    void* args[] = { (void*)&x, (void*)&emb, (void*)&Wi1, (void*)&Wh1,
                     (void*)&b1, (void*)&Wi2, (void*)&Wh2, (void*)&b2,
                     (void*)&hb, (void*)&p1, (void*)&p2,
                     (void*)&cntA, (void*)&cntB };
    hipLaunchCooperativeKernel((const void*)rnn_scan, dim3(NBLK_), dim3(256),
                               args, 0, stream);

    dense_sigmoid<<<64, 64, 0, stream>>>(hb + 196608, Wd, bd, out);
}

// Round 10
// 15856.909 us; speedup vs baseline: 2.3856x; 1.1593x over previous
//
#include <hip/hip_runtime.h>

#define B_   64
#define S_   512
#define EMB_ 512
#define HID_ 1024
#define NBLK_ 256

typedef float    f32x4 __attribute__((ext_vector_type(4)));
typedef unsigned u32x4 __attribute__((ext_vector_type(4)));

// Coherent (Infinity-Cache) access: sc0 sc1 bypasses L1+L2 -> no cache-wide
// fences needed for cross-XCD exchange. Proven in R5/R8.
// RULE: inline-asm loads get NO compiler-inserted s_waitcnt. Every consumer
// must wait explicitly (R8 pattern), or the wait must be embedded (poll).
__device__ __forceinline__ f32x4 ld_coh4(const float* p) {
    f32x4 d;
    asm volatile("global_load_dwordx4 %0, %1, off sc0 sc1" : "=v"(d) : "v"(p));
    return d;
}
__device__ __forceinline__ float ld_coh1(const float* p) {
    float d;
    asm volatile("global_load_dword %0, %1, off sc0 sc1" : "=v"(d) : "v"(p));
    return d;
}
// Poll load with the vmcnt wait EMBEDDED — result is valid at asm exit.
__device__ __forceinline__ u32x4 ld_coh4u_wait(const unsigned* p) {
    u32x4 d;
    asm volatile("global_load_dwordx4 %0, %1, off sc0 sc1\n\t"
                 "s_waitcnt vmcnt(0)"
                 : "=v"(d) : "v"(p) : "memory");
    return d;
}
__device__ __forceinline__ void st_coh4(float* p, f32x4 v) {
    asm volatile("global_store_dwordx4 %0, %1, off sc0 sc1" :: "v"(p), "v"(v) : "memory");
}
__device__ __forceinline__ void st_coh1(float* p, float v) {
    asm volatile("global_store_dword %0, %1, off sc0 sc1" :: "v"(p), "v"(v) : "memory");
}
__device__ __forceinline__ void st_coh1u(unsigned* p, unsigned v) {
    asm volatile("global_store_dword %0, %1, off sc0 sc1" :: "v"(p), "v"(v) : "memory");
}

// Flag barrier: arrival = one plain flag store per block (own slot, zero
// contention); wait = wave0 lanes poll 4 flags each via dwordx4 (+wait).
__device__ __forceinline__ void flag_barrier(unsigned* flags, int bk, int tid) {
    asm volatile("s_waitcnt vmcnt(0)" ::: "memory");  // own stores at IC
    __syncthreads();                                  // all waves drained
    if (tid == 0) st_coh1u(flags + bk, 1u);
    if (tid < 64) {
        const unsigned* fp = flags + tid * 4;
        for (;;) {
            u32x4 v = ld_coh4u_wait(fp);
            if (v[0] && v[1] && v[2] && v[3]) break;
            __builtin_amdgcn_s_sleep(1);
        }
    }
    __syncthreads();
}

// ---------------------------------------------------------------------------
// Persistent split-k scan. 256 blocks x 256 threads. Same structure as R8:
// block (kg = bk>>5, cg = bk&31); phase A computes partials over its k-slice,
// phase B reduces 8 partials for its 4 output cols. Two flag barriers/step.
// ---------------------------------------------------------------------------
__global__ __launch_bounds__(256, 1) void rnn_scan(
    const int* __restrict__ x, const float* __restrict__ emb,
    const float* __restrict__ Wi1, const float* __restrict__ Wh1,
    const float* __restrict__ b1,  const float* __restrict__ Wi2,
    const float* __restrict__ Wh2, const float* __restrict__ b2,
    float* __restrict__ hb, float* __restrict__ p1, float* __restrict__ p2,
    unsigned int* __restrict__ flagsA, unsigned int* __restrict__ flagsB)
{
    __shared__ float w1s[128 * 32];   // Wh1 slice [k][c]
    __shared__ float w2s[128 * 32];   // Wi2 slice
    __shared__ float w3s[128 * 32];   // Wh2 slice
    __shared__ float wxs[64 * 32];    // Wi1 slice [kx][c]
    __shared__ float h1s[64 * 132];   // h1 k-slice, padded stride
    __shared__ float h2s[64 * 132];
    __shared__ float xs [64 * 68];    // emb k-slice, padded stride
    __shared__ int   toks[64];

    const int tid = threadIdx.x;
    const int bk  = blockIdx.x;
    const int kg  = bk >> 5;          // 0..7   k-group
    const int cg  = bk & 31;          // 0..31  col-group (32 cols)
    const int k0  = kg * 128;         // h-k slice base (HID)
    const int kx0 = kg * 64;          // x-k slice base (EMB)
    const int cs0 = cg * 32;          // col-slice base

    // ---- stage weight slices (once) ----
    for (int idx = tid; idx < 1024; idx += 256) {        // 128*32 /4
        int k = idx >> 3, c4 = (idx & 7) * 4;
        *(f32x4*)&w1s[k * 32 + c4] = *(const f32x4*)(Wh1 + (size_t)(k0 + k) * HID_ + cs0 + c4);
        *(f32x4*)&w2s[k * 32 + c4] = *(const f32x4*)(Wi2 + (size_t)(k0 + k) * HID_ + cs0 + c4);
        *(f32x4*)&w3s[k * 32 + c4] = *(const f32x4*)(Wh2 + (size_t)(k0 + k) * HID_ + cs0 + c4);
    }
    for (int idx = tid; idx < 512; idx += 256) {         // 64*32 /4
        int k = idx >> 3, c4 = (idx & 7) * 4;
        *(f32x4*)&wxs[k * 32 + c4] = *(const f32x4*)(Wi1 + (size_t)(kx0 + k) * HID_ + cs0 + c4);
    }

    const int row = tid >> 2;         // 0..63 (batch row; also phase-B row)
    const int cq  = tid & 3;          // 0..3
    const int cb  = cq * 8;           // col offset within 32-col slice

    const int c0   = bk * 4;          // phase-B output col base
    const int ocol = c0 + cq;         // phase-B output col
    const float b1v = b1[ocol];
    const float b2v = b2[ocol];

    float* h1buf[2] = { hb, hb + 65536 };
    float* h2buf[2] = { hb + 131072, hb + 196608 };

    __syncthreads();

    for (int i = 0; i <= S_; ++i) {
        const float* h1src = h1buf[(i + 1) & 1];   // h1(i-1)
        const float* h2src = h2buf[i & 1];         // h2(i-2)

        // ---- token ids for this step (dummy at i==S_, result unused) ----
        const int ii = (i < S_) ? i : 0;
        if (tid < 64) toks[tid] = x[tid * S_ + ii];

        // ---- issue h k-slice IC loads ----
        f32x4 va[8], vb[8];
#pragma unroll
        for (int j = 0; j < 8; ++j) {
            int idx = tid + j * 256;           // 0..2047 f32x4 units
            int r   = idx >> 5;                // row
            int kk  = (idx & 31) * 4;          // k within slice
            va[j] = ld_coh4(h1src + r * HID_ + k0 + kk);
            vb[j] = ld_coh4(h2src + r * HID_ + k0 + kk);
        }
        __syncthreads();                        // toks visible
        // ---- gather emb x-slice (plain cached; emb is read-only) ----
        f32x4 xg[4];
        {
            int kk = (tid & 3) * 16;
            const float* ep = emb + (size_t)toks[row] * EMB_ + kx0 + kk;
#pragma unroll
            for (int j = 0; j < 4; ++j) xg[j] = *(const f32x4*)(ep + j * 4);
        }
        asm volatile("s_waitcnt vmcnt(0)" ::: "memory");
        __builtin_amdgcn_sched_barrier(0);
        // ---- write staged data to LDS ----
#pragma unroll
        for (int j = 0; j < 8; ++j) {
            int idx = tid + j * 256;
            int r   = idx >> 5;
            int kk  = (idx & 31) * 4;
            *(f32x4*)&h1s[r * 132 + kk] = va[j];
            *(f32x4*)&h2s[r * 132 + kk] = vb[j];
        }
        {
            int kk = (tid & 3) * 16;
#pragma unroll
            for (int j = 0; j < 4; ++j) *(f32x4*)&xs[row * 68 + kk + j * 4] = xg[j];
        }
        __syncthreads();

        // ---- phase A compute: partials for 8 cols (cb..cb+8) ----
        f32x4 a1lo = {0,0,0,0}, a1hi = {0,0,0,0};
        f32x4 a2lo = {0,0,0,0}, a2hi = {0,0,0,0};

        const float* h1r = &h1s[row * 132];
        const float* h2r = &h2s[row * 132];
#pragma unroll 8
        for (int kq = 0; kq < 128; kq += 4) {
            f32x4 hv1 = *(const f32x4*)(h1r + kq);
            f32x4 hv2 = *(const f32x4*)(h2r + kq);
#pragma unroll
            for (int j = 0; j < 4; ++j) {
                const int k = kq + j;
                f32x4 wa0 = *(const f32x4*)&w1s[k * 32 + cb];
                f32x4 wa1 = *(const f32x4*)&w1s[k * 32 + cb + 4];
                f32x4 wb0 = *(const f32x4*)&w2s[k * 32 + cb];
                f32x4 wb1 = *(const f32x4*)&w2s[k * 32 + cb + 4];
                f32x4 wc0 = *(const f32x4*)&w3s[k * 32 + cb];
                f32x4 wc1 = *(const f32x4*)&w3s[k * 32 + cb + 4];
                float h1x = hv1[j], h2x = hv2[j];
                a1lo += h1x * wa0;  a1hi += h1x * wa1;
                a2lo += h1x * wb0 + h2x * wc0;
                a2hi += h1x * wb1 + h2x * wc1;
            }
        }
        const float* xr = &xs[row * 68];
#pragma unroll 4
        for (int kq = 0; kq < 64; kq += 4) {
            f32x4 xv = *(const f32x4*)(xr + kq);
#pragma unroll
            for (int j = 0; j < 4; ++j) {
                const int k = kq + j;
                f32x4 wx0 = *(const f32x4*)&wxs[k * 32 + cb];
                f32x4 wx1 = *(const f32x4*)&wxs[k * 32 + cb + 4];
                a1lo += xv[j] * wx0;  a1hi += xv[j] * wx1;
            }
        }

        // ---- write partials (IC) ----
        {
            float* pp1 = p1 + ((size_t)kg * 64 + row) * HID_ + cs0 + cb;
            float* pp2 = p2 + ((size_t)kg * 64 + row) * HID_ + cs0 + cb;
            st_coh4(pp1,     a1lo); st_coh4(pp1 + 4, a1hi);
            st_coh4(pp2,     a2lo); st_coh4(pp2 + 4, a2hi);
        }

        // ---- barrier A (flag-based, contention-free) ----
        flag_barrier(flagsA + (size_t)i * 256, bk, tid);

        // ---- phase B: reduce 8 partials, bias + tanh, write h ----
        float part1[8], part2[8];
#pragma unroll
        for (int g8 = 0; g8 < 8; ++g8) {
            part1[g8] = ld_coh1(p1 + ((size_t)g8 * 64 + row) * HID_ + ocol);
            part2[g8] = ld_coh1(p2 + ((size_t)g8 * 64 + row) * HID_ + ocol);
        }
        asm volatile("s_waitcnt vmcnt(0)" ::: "memory");
        __builtin_amdgcn_sched_barrier(0);
        float s1 = b1v, s2 = b2v;
#pragma unroll
        for (int g8 = 0; g8 < 8; ++g8) { s1 += part1[g8]; s2 += part2[g8]; }

        if (i < S_)
            st_coh1(h1buf[i & 1] + row * HID_ + ocol, tanhf(s1));
        if (i >= 1)
            st_coh1(h2buf[(i + 1) & 1] + row * HID_ + ocol, tanhf(s2));

        // ---- barrier B ----
        if (i < S_)
            flag_barrier(flagsB + (size_t)i * 256, bk, tid);
    }
    // h2(S-1) sits in h2buf[1] (= hb + 196608)
}

// ---------------------------------------------------------------------------
// out[b] = sigmoid(h2_last[b,:] @ Wd + bd)
// ---------------------------------------------------------------------------
__global__ void dense_sigmoid(const float* __restrict__ h2,
                              const float* __restrict__ Wd,
                              const float* __restrict__ bd,
                              float* __restrict__ out)
{
    int b = blockIdx.x, lane = threadIdx.x;
    float s = 0.f;
    for (int j = lane; j < HID_; j += 64) s += h2[b * HID_ + j] * Wd[j];
#pragma unroll
    for (int off = 32; off > 0; off >>= 1) s += __shfl_down(s, off, 64);
    if (lane == 0) out[b] = 1.f / (1.f + expf(-(s + bd[0])));
}

// ---------------------------------------------------------------------------
// ws layout (bytes):
//   hb     @ 0          1,048,576  (4 h buffers fp32)
//   flagsA @ 1,048,576    525,312  (513 steps x 256 u32)
//   flagsB @ 1,573,888    524,288  (512 steps x 256 u32)
//   p1     @ 2,098,176  2,097,152  (8 kg x 64 rows x 1024 cols fp32)
//   p2     @ 4,195,328  2,097,152
// total 6,292,480 B.  memset zeroes hb+flagsA+flagsB = 2,098,176 B.
// (p1/p2 are written before read every step -> no init needed.)
// ---------------------------------------------------------------------------
extern "C" void kernel_launch(void* const* d_in, const int* in_sizes, int n_in,
                              void* d_out, int out_size, void* d_ws, size_t ws_size,
                              hipStream_t stream)
{
    const int*   x   = (const int*)  d_in[0];
    const float* emb = (const float*)d_in[1];
    const float* Wi1 = (const float*)d_in[2];
    const float* Wh1 = (const float*)d_in[3];
    const float* b1  = (const float*)d_in[4];
    const float* Wi2 = (const float*)d_in[5];
    const float* Wh2 = (const float*)d_in[6];
    const float* b2  = (const float*)d_in[7];
    const float* Wd  = (const float*)d_in[8];
    const float* bd  = (const float*)d_in[9];
    float* out = (float*)d_out;

    char* w = (char*)d_ws;
    float*        hb     = (float*)w;
    unsigned int* flagsA = (unsigned int*)(w + 1048576);
    unsigned int* flagsB = (unsigned int*)(w + 1573888);
    float*        p1     = (float*)(w + 2098176);
    float*        p2     = (float*)(w + 4195328);

    hipMemsetAsync(w, 0, 2098176, stream);

    void* args[] = { (void*)&x, (void*)&emb, (void*)&Wi1, (void*)&Wh1,
                     (void*)&b1, (void*)&Wi2, (void*)&Wh2, (void*)&b2,
                     (void*)&hb, (void*)&p1, (void*)&p2,
                     (void*)&flagsA, (void*)&flagsB };
    hipLaunchCooperativeKernel((const void*)rnn_scan, dim3(NBLK_), dim3(256),
                               args, 0, stream);

    dense_sigmoid<<<64, 64, 0, stream>>>(hb + 196608, Wd, bd, out);
}

// Round 11
// 14855.811 us; speedup vs baseline: 2.5464x; 1.0674x over previous
//
#include <hip/hip_runtime.h>

#define B_   64
#define S_   512
#define EMB_ 512
#define HID_ 1024
#define NBLK_ 256

typedef float    f32x4 __attribute__((ext_vector_type(4)));
typedef unsigned u32x4 __attribute__((ext_vector_type(4)));

// Coherent (Infinity-Cache) access: sc0 sc1 bypasses L1+L2 -> no cache-wide
// fences needed for cross-XCD exchange. Proven in R5/R8/R10.
// RULE: inline-asm loads get NO compiler-inserted s_waitcnt. Every consumer
// must wait explicitly, or the wait must be embedded (poll).
__device__ __forceinline__ f32x4 ld_coh4(const float* p) {
    f32x4 d;
    asm volatile("global_load_dwordx4 %0, %1, off sc0 sc1" : "=v"(d) : "v"(p));
    return d;
}
__device__ __forceinline__ float ld_coh1(const float* p) {
    float d;
    asm volatile("global_load_dword %0, %1, off sc0 sc1" : "=v"(d) : "v"(p));
    return d;
}
// Poll load with the vmcnt wait EMBEDDED — result is valid at asm exit.
__device__ __forceinline__ u32x4 ld_coh4u_wait(const unsigned* p) {
    u32x4 d;
    asm volatile("global_load_dwordx4 %0, %1, off sc0 sc1\n\t"
                 "s_waitcnt vmcnt(0)"
                 : "=v"(d) : "v"(p) : "memory");
    return d;
}
__device__ __forceinline__ void st_coh4(float* p, f32x4 v) {
    asm volatile("global_store_dwordx4 %0, %1, off sc0 sc1" :: "v"(p), "v"(v) : "memory");
}
__device__ __forceinline__ void st_coh1(float* p, float v) {
    asm volatile("global_store_dword %0, %1, off sc0 sc1" :: "v"(p), "v"(v) : "memory");
}
__device__ __forceinline__ void st_coh1u(unsigned* p, unsigned v) {
    asm volatile("global_store_dword %0, %1, off sc0 sc1" :: "v"(p), "v"(v) : "memory");
}

// Flag barrier: arrival = one plain flag store per block (own slot, zero
// contention); wait = wave0 lanes poll 4 flags each via dwordx4 (+wait).
__device__ __forceinline__ void flag_barrier(unsigned* flags, int bk, int tid) {
    asm volatile("s_waitcnt vmcnt(0)" ::: "memory");  // own stores at IC
    __syncthreads();                                  // all waves drained
    if (tid == 0) st_coh1u(flags + bk, 1u);
    if (tid < 64) {
        const unsigned* fp = flags + tid * 4;
        for (;;) {
            u32x4 v = ld_coh4u_wait(fp);
            if (v[0] && v[1] && v[2] && v[3]) break;
            __builtin_amdgcn_s_sleep(1);
        }
    }
    __syncthreads();
}

// ---------------------------------------------------------------------------
// Kernel A: X1[t][b][n] = emb[x[b][t]][:] @ Wi1[:,n] + b1[n]   (fp32; the
// recurrence is chaotic — no reduced precision anywhere feeding it, R6)
// ---------------------------------------------------------------------------
__global__ __launch_bounds__(256) void embed_gemm(
    const int* __restrict__ x, const float* __restrict__ emb,
    const float* __restrict__ Wi1, const float* __restrict__ b1,
    float* __restrict__ X1)
{
    __shared__ int   tok[128];
    __shared__ float aT[32][132];
    __shared__ float bl[32][68];

    const int tid = threadIdx.x;
    const int m0  = blockIdx.y * 128;
    const int n0  = blockIdx.x * 64;

    if (tid < 128) {
        int m = m0 + tid;
        tok[tid] = x[(m & 63) * S_ + (m >> 6)];
    }
    __syncthreads();

    const int tx = tid & 15;
    const int ty = tid >> 4;

    float acc[8][4];
#pragma unroll
    for (int r = 0; r < 8; ++r)
#pragma unroll
        for (int c = 0; c < 4; ++c) acc[r][c] = 0.f;

    for (int kt = 0; kt < EMB_; kt += 32) {
#pragma unroll
        for (int j = 0; j < 4; ++j) {
            int idx = tid + j * 256;
            int r   = idx >> 3;
            int k4  = (idx & 7) * 4;
            float4 v = *(const float4*)(emb + (size_t)tok[r] * EMB_ + kt + k4);
            aT[k4 + 0][r] = v.x; aT[k4 + 1][r] = v.y;
            aT[k4 + 2][r] = v.z; aT[k4 + 3][r] = v.w;
        }
#pragma unroll
        for (int j = 0; j < 2; ++j) {
            int idx = tid + j * 256;
            int k   = idx >> 4;
            int c4  = (idx & 15) * 4;
            *(float4*)&bl[k][c4] =
                *(const float4*)(Wi1 + (size_t)(kt + k) * HID_ + n0 + c4);
        }
        __syncthreads();

#pragma unroll 4
        for (int k = 0; k < 32; ++k) {
            float4 a0 = *(const float4*)&aT[k][ty * 8];
            float4 a1 = *(const float4*)&aT[k][ty * 8 + 4];
            float4 bv = *(const float4*)&bl[k][tx * 4];
            float ar[8] = {a0.x, a0.y, a0.z, a0.w, a1.x, a1.y, a1.z, a1.w};
            float bc[4] = {bv.x, bv.y, bv.z, bv.w};
#pragma unroll
            for (int r = 0; r < 8; ++r)
#pragma unroll
                for (int c = 0; c < 4; ++c) acc[r][c] += ar[r] * bc[c];
        }
        __syncthreads();
    }

    float4 bias = *(const float4*)(b1 + n0 + tx * 4);
#pragma unroll
    for (int r = 0; r < 8; ++r) {
        int m = m0 + ty * 8 + r;
        float4 o;
        o.x = acc[r][0] + bias.x; o.y = acc[r][1] + bias.y;
        o.z = acc[r][2] + bias.z; o.w = acc[r][3] + bias.w;
        *(float4*)(X1 + (size_t)m * HID_ + n0 + tx * 4) = o;
    }
}

// ---------------------------------------------------------------------------
// Kernel B: persistent split-k scan (R10 structure, emb gather removed).
// Block (kg = bk>>5, cg = bk&31): phase A stages h k-slices via IC, computes
// partials for its 32 cols; barrier A; phase B reduces 8 partials for its 4
// cols, adds X1 (plain cached, sequential) + bias, tanh, writes h; barrier B.
// ---------------------------------------------------------------------------
__global__ __launch_bounds__(256, 1) void rnn_scan(
    const float* __restrict__ X1, const float* __restrict__ Wh1,
    const float* __restrict__ b1,  const float* __restrict__ Wi2,
    const float* __restrict__ Wh2, const float* __restrict__ b2,
    float* __restrict__ hb, float* __restrict__ p1, float* __restrict__ p2,
    unsigned int* __restrict__ flagsA, unsigned int* __restrict__ flagsB)
{
    __shared__ float w1s[128 * 32];   // Wh1 slice [k][c]
    __shared__ float w2s[128 * 32];   // Wi2 slice
    __shared__ float w3s[128 * 32];   // Wh2 slice
    __shared__ float h1s[64 * 132];   // h1 k-slice, padded stride
    __shared__ float h2s[64 * 132];

    const int tid = threadIdx.x;
    const int bk  = blockIdx.x;
    const int kg  = bk >> 5;          // 0..7   k-group
    const int cg  = bk & 31;          // 0..31  col-group (32 cols)
    const int k0  = kg * 128;         // h-k slice base (HID)
    const int cs0 = cg * 32;          // col-slice base

    // ---- stage weight slices (once) ----
    for (int idx = tid; idx < 1024; idx += 256) {        // 128*32 /4
        int k = idx >> 3, c4 = (idx & 7) * 4;
        *(f32x4*)&w1s[k * 32 + c4] = *(const f32x4*)(Wh1 + (size_t)(k0 + k) * HID_ + cs0 + c4);
        *(f32x4*)&w2s[k * 32 + c4] = *(const f32x4*)(Wi2 + (size_t)(k0 + k) * HID_ + cs0 + c4);
        *(f32x4*)&w3s[k * 32 + c4] = *(const f32x4*)(Wh2 + (size_t)(k0 + k) * HID_ + cs0 + c4);
    }

    const int row = tid >> 2;         // 0..63 (batch row; also phase-B row)
    const int cq  = tid & 3;          // 0..3
    const int cb  = cq * 8;           // col offset within 32-col slice

    const int ocol = bk * 4 + cq;     // phase-B output col
    const float b1v = b1[ocol];
    const float b2v = b2[ocol];

    float* h1buf[2] = { hb, hb + 65536 };
    float* h2buf[2] = { hb + 131072, hb + 196608 };

    __syncthreads();

    for (int i = 0; i <= S_; ++i) {
        const float* h1src = h1buf[(i + 1) & 1];   // h1(i-1)
        const float* h2src = h2buf[i & 1];         // h2(i-2)

        // ---- issue h k-slice IC loads ----
        f32x4 va[8], vb[8];
#pragma unroll
        for (int j = 0; j < 8; ++j) {
            int idx = tid + j * 256;           // 0..2047 f32x4 units
            int r   = idx >> 5;                // row
            int kk  = (idx & 31) * 4;          // k within slice
            va[j] = ld_coh4(h1src + r * HID_ + k0 + kk);
            vb[j] = ld_coh4(h2src + r * HID_ + k0 + kk);
        }
        asm volatile("s_waitcnt vmcnt(0)" ::: "memory");
        __builtin_amdgcn_sched_barrier(0);
        // ---- write staged data to LDS ----
#pragma unroll
        for (int j = 0; j < 8; ++j) {
            int idx = tid + j * 256;
            int r   = idx >> 5;
            int kk  = (idx & 31) * 4;
            *(f32x4*)&h1s[r * 132 + kk] = va[j];
            *(f32x4*)&h2s[r * 132 + kk] = vb[j];
        }
        __syncthreads();

        // ---- phase A compute: partials for 8 cols (cb..cb+8) ----
        f32x4 a1lo = {0,0,0,0}, a1hi = {0,0,0,0};
        f32x4 a2lo = {0,0,0,0}, a2hi = {0,0,0,0};

        const float* h1r = &h1s[row * 132];
        const float* h2r = &h2s[row * 132];
#pragma unroll 8
        for (int kq = 0; kq < 128; kq += 4) {
            f32x4 hv1 = *(const f32x4*)(h1r + kq);
            f32x4 hv2 = *(const f32x4*)(h2r + kq);
#pragma unroll
            for (int j = 0; j < 4; ++j) {
                const int k = kq + j;
                f32x4 wa0 = *(const f32x4*)&w1s[k * 32 + cb];
                f32x4 wa1 = *(const f32x4*)&w1s[k * 32 + cb + 4];
                f32x4 wb0 = *(const f32x4*)&w2s[k * 32 + cb];
                f32x4 wb1 = *(const f32x4*)&w2s[k * 32 + cb + 4];
                f32x4 wc0 = *(const f32x4*)&w3s[k * 32 + cb];
                f32x4 wc1 = *(const f32x4*)&w3s[k * 32 + cb + 4];
                float h1x = hv1[j], h2x = hv2[j];
                a1lo += h1x * wa0;  a1hi += h1x * wa1;
                a2lo += h1x * wb0 + h2x * wc0;
                a2hi += h1x * wb1 + h2x * wc1;
            }
        }

        // ---- write partials (IC) ----
        {
            float* pp1 = p1 + ((size_t)kg * 64 + row) * HID_ + cs0 + cb;
            float* pp2 = p2 + ((size_t)kg * 64 + row) * HID_ + cs0 + cb;
            st_coh4(pp1,     a1lo); st_coh4(pp1 + 4, a1hi);
            st_coh4(pp2,     a2lo); st_coh4(pp2 + 4, a2hi);
        }

        // ---- barrier A (flag-based, contention-free) ----
        flag_barrier(flagsA + (size_t)i * 256, bk, tid);

        // ---- phase B: reduce 8 partials, + X1 + bias, tanh, write h ----
        float part1[8], part2[8];
#pragma unroll
        for (int g8 = 0; g8 < 8; ++g8) {
            part1[g8] = ld_coh1(p1 + ((size_t)g8 * 64 + row) * HID_ + ocol);
            part2[g8] = ld_coh1(p2 + ((size_t)g8 * 64 + row) * HID_ + ocol);
        }
        asm volatile("s_waitcnt vmcnt(0)" ::: "memory");
        __builtin_amdgcn_sched_barrier(0);
        float s1 = b1v, s2 = b2v;
#pragma unroll
        for (int g8 = 0; g8 < 8; ++g8) { s1 += part1[g8]; s2 += part2[g8]; }

        if (i < S_) {
            // X1 term: plain cached load (sequential, written by embed_gemm;
            // visible via kernel-end release / kernel-start acquire)
            float xv = X1[((size_t)i * B_ + row) * HID_ + ocol];
            st_coh1(h1buf[i & 1] + row * HID_ + ocol, tanhf(xv + s1));
        }
        if (i >= 1)
            st_coh1(h2buf[(i + 1) & 1] + row * HID_ + ocol, tanhf(s2));

        // ---- barrier B ----
        if (i < S_)
            flag_barrier(flagsB + (size_t)i * 256, bk, tid);
    }
    // h2(S-1) sits in h2buf[1] (= hb + 196608)
}

// ---------------------------------------------------------------------------
// out[b] = sigmoid(h2_last[b,:] @ Wd + bd)
// ---------------------------------------------------------------------------
__global__ void dense_sigmoid(const float* __restrict__ h2,
                              const float* __restrict__ Wd,
                              const float* __restrict__ bd,
                              float* __restrict__ out)
{
    int b = blockIdx.x, lane = threadIdx.x;
    float s = 0.f;
    for (int j = lane; j < HID_; j += 64) s += h2[b * HID_ + j] * Wd[j];
#pragma unroll
    for (int off = 32; off > 0; off >>= 1) s += __shfl_down(s, off, 64);
    if (lane == 0) out[b] = 1.f / (1.f + expf(-(s + bd[0])));
}

// ---------------------------------------------------------------------------
// ws layout (bytes):
//   hb     @ 0          1,048,576  (4 h buffers fp32)
//   flagsA @ 1,048,576    525,312  (513 steps x 256 u32)
//   flagsB @ 1,573,888    524,288  (512 steps x 256 u32)
//   p1     @ 2,098,176  2,097,152  (8 kg x 64 rows x 1024 cols fp32)
//   p2     @ 4,195,328  2,097,152
//   X1     @ 6,292,480  134,217,728 (S*B*HID fp32)
// total 140,510,208 B.  memset zeroes hb+flagsA+flagsB = 2,098,176 B.
// (p1/p2/X1 are written before read -> no init needed.)
// ---------------------------------------------------------------------------
extern "C" void kernel_launch(void* const* d_in, const int* in_sizes, int n_in,
                              void* d_out, int out_size, void* d_ws, size_t ws_size,
                              hipStream_t stream)
{
    const int*   x   = (const int*)  d_in[0];
    const float* emb = (const float*)d_in[1];
    const float* Wi1 = (const float*)d_in[2];
    const float* Wh1 = (const float*)d_in[3];
    const float* b1  = (const float*)d_in[4];
    const float* Wi2 = (const float*)d_in[5];
    const float* Wh2 = (const float*)d_in[6];
    const float* b2  = (const float*)d_in[7];
    const float* Wd  = (const float*)d_in[8];
    const float* bd  = (const float*)d_in[9];
    float* out = (float*)d_out;

    char* w = (char*)d_ws;
    float*        hb     = (float*)w;
    unsigned int* flagsA = (unsigned int*)(w + 1048576);
    unsigned int* flagsB = (unsigned int*)(w + 1573888);
    float*        p1     = (float*)(w + 2098176);
    float*        p2     = (float*)(w + 4195328);
    float*        X1     = (float*)(w + 6292480);

    hipMemsetAsync(w, 0, 2098176, stream);

    dim3 gA(HID_ / 64, (S_ * B_) / 128);
    embed_gemm<<<gA, dim3(256), 0, stream>>>(x, emb, Wi1, b1, X1);

    const float* X1c = X1;
    void* args[] = { (void*)&X1c, (void*)&Wh1, (void*)&b1, (void*)&Wi2,
                     (void*)&Wh2, (void*)&b2, (void*)&hb, (void*)&p1,
                     (void*)&p2, (void*)&flagsA, (void*)&flagsB };
    hipLaunchCooperativeKernel((const void*)rnn_scan, dim3(NBLK_), dim3(256),
                               args, 0, stream);

    dense_sigmoid<<<64, 64, 0, stream>>>(hb + 196608, Wd, bd, out);
}